// Round 10
// baseline (193.870 us; speedup 1.0000x reference)
//
#include <hip/hip_runtime.h>
#include <stdint.h>

#define BATCH 16
#define H 512
#define W 512
#define HW (H * W)
#define NTOT (BATCH * HW)
#define NWORDS (NTOT / 64)      // 65536 packed words, 8 per row, 4096 per image

#define SROWS 16                // CCL strip = 16 rows
#define SWORDS 128              // words per CCL strip
#define SPIX 8192               // pixels per CCL strip
#define NSTRIPS (NWORDS / SWORDS)   // 512 strips (never straddle images)
#define IMG_STRIPS 32               // strips per image

#define MAXR 4096                   // max runs per strip (128 words x 32)
#define NR (NSTRIPS * MAXR)         // run-id space: 2M ids, 8 MB per array

#define SPIN_LIMIT (1 << 20)        // barrier spin cap: give up loudly
#define WALK_LIMIT (1 << 16)        // UF walk cap: hang -> wrong answer, not hang

// Persistent barrier flags (module lifetime, zero-init); monotone epochs.
__device__ int g_flags[BATCH * 32];

// ---------------------------------------------------------------------------
// Agent-scope relaxed accessors (coherence-point). r4 proved fence-free sc1
// is coherent cross-XCD. r5/r6/r7 nulls localized the floor to SAME-ADDRESS
// sc1 serialization — r9 removes those reads via a per-strip LDS root cache.
// parS is DEDICATED LDS (r8's union with mo/kd corrupted it -> hang).
// r10 = r9 + WALK_LIMIT guards on every UF loop: any unforeseen corruption
// terminates with a wrong answer (diagnosable) instead of a dead container.
// ---------------------------------------------------------------------------
__device__ __forceinline__ int ald(const int* p) {
    return __hip_atomic_load((int*)p, __ATOMIC_RELAXED, __HIP_MEMORY_SCOPE_AGENT);
}
__device__ __forceinline__ void ast(int* p, int v) {
    __hip_atomic_store(p, v, __ATOMIC_RELAXED, __HIP_MEMORY_SCOPE_AGENT);
}
__device__ __forceinline__ uint64_t ald64(const uint64_t* p) {
    return __hip_atomic_load((uint64_t*)p, __ATOMIC_RELAXED, __HIP_MEMORY_SCOPE_AGENT);
}
__device__ __forceinline__ void ast64(uint64_t* p, uint64_t v) {
    __hip_atomic_store(p, v, __ATOMIC_RELAXED, __HIP_MEMORY_SCOPE_AGENT);
}

// Union-find over run ids (global): atomicMin keeps parent <= child -> acyclic.
__device__ __forceinline__ int find_root_c(int* L, int x) {
    int r = x, p = ald(&L[r]), g = 0;
    while (p != r && ++g < WALK_LIMIT) { r = p; p = ald(&L[r]); }
    if (ald(&L[x]) != r) atomicMin(&L[x], r);
    return r;
}

__device__ __forceinline__ int walk_root(const int* L, int x) {  // read-only
    int r = x, p = ald(&L[r]), g = 0;
    while (p != r && ++g < WALK_LIMIT) { r = p; p = ald(&L[r]); }
    return r;
}

__device__ void merge_uf(int* L, int a, int b) {
    int g = 0;
    while (++g < WALK_LIMIT) {
        a = find_root_c(L, a);
        b = find_root_c(L, b);
        if (a == b) return;
        int lo = a < b ? a : b;
        int hi = a < b ? b : a;
        int old = atomicMin(&L[hi], lo);
        if (old == hi) return;
        a = lo; b = old;
    }
}

__device__ __forceinline__ int find_root_lds(const int* P, int x) {
    int r = x, p = P[r], g = 0;
    while (p != r && ++g < WALK_LIMIT) { r = p; p = P[r]; }
    return r;
}

__device__ void merge_lds(int* P, int a, int b) {
    int g = 0;
    while (++g < WALK_LIMIT) {
        a = find_root_lds(P, a);
        b = find_root_lds(P, b);
        if (a == b) return;
        int lo = a < b ? a : b;
        int hi = a < b ? b : a;
        int old = atomicMin(&P[hi], lo);
        if (old == hi) return;
        a = lo; b = old;
    }
}

// rid of the run containing bit i of word m (global-side halo resolution)
__device__ __forceinline__ int run_of(uint64_t m, int i, int cvrid, int wr) {
    uint64_t below = i ? ((~m) & ((1ull << i) - 1)) : 0ull;
    if (below == 0) return (cvrid >= 0) ? cvrid : wr;
    int s = 64 - __builtin_clzll(below);           // start bit of i's run
    uint64_t starts = m & ~((m << 1) | ((cvrid >= 0) ? 1ull : 0ull));
    return wr + __popcll(starts & ((1ull << s) - 1));
}

__device__ __forceinline__ int run_of_lds(uint64_t m, int i, int cvrid,
                                          uint64_t starts, int wb) {
    uint64_t below = i ? ((~m) & ((1ull << i) - 1)) : 0ull;
    if (below == 0) return (cvrid >= 0) ? cvrid : wb;
    int s = 64 - __builtin_clzll(below);
    return wb + __popcll(starts & ((1ull << s) - 1));
}

// ---------------------------------------------------------------------------
// 256-slot LDS root hash (per strip). Static after the building sync.
// ---------------------------------------------------------------------------
__device__ __forceinline__ int hash_insert(int key, int cnt, int* hk, int* hcnt) {
    uint32_t h = ((uint32_t)key * 2654435761u) >> 24;
    for (int p = 0; p < 16; ++p) {
        int s = (h + p) & 255;
        int k = hk[s];
        if (k == -1) k = atomicCAS(&hk[s], -1, key);
        if (k == -1 || k == key) { atomicAdd(&hcnt[s], cnt); return s; }
    }
    return -1;                                     // overflow (never with blobs)
}
__device__ __forceinline__ int hash_find(int key, const int* hk) {
    uint32_t h = ((uint32_t)key * 2654435761u) >> 24;
    for (int p = 0; p < 16; ++p) {
        int s = (h + p) & 255;
        if (hk[s] == key) return s;
        if (hk[s] == -1) return -1;
    }
    return -1;
}

// ---------------------------------------------------------------------------
// flatten_map: LDS-cached flatten. A) aggregate per strip-root counts in LDS
// (0 global loads); B) ONE global find per distinct strip-root (parallel) +
// sizes add; C) publish L[rid]=final root for halo consumers + exact ncomp
// count at rid==root. par must hold this CCL round's strip UF.
// ---------------------------------------------------------------------------
__device__ void flatten_map(uint64_t m, int cvL, int wb, const int* par,
                            int gbase, int* L, int* sizes, int* ncomp_img,
                            int t, int* hk, int* hcnt, int* hrs) {
    for (int i = t; i < 256; i += 256) { hk[i] = -1; hcnt[i] = 0; }
    __syncthreads();
    if (t < SWORDS && m) {                        // A: LDS aggregation
        uint64_t rem = m; int rk = 0;
        while (rem) {
            int s = __builtin_ctzll(rem);
            uint64_t rest = rem >> s;
            uint64_t nr = ~rest;
            int len = nr ? __builtin_ctzll(nr) : (64 - s);
            uint64_t piece = ((len >= 64) ? ~0ull : ((1ull << len) - 1)) << s;
            bool ini = !(s == 0 && cvL >= 0);
            int rl = ini ? (wb + rk) : cvL; rk += ini ? 1 : 0;
            int rloc = find_root_lds(par, rl);
            int cnt = __popcll(piece);
            if (hash_insert(rloc, cnt, hk, hcnt) < 0)
                atomicAdd(&sizes[find_root_c(L, gbase + rloc)], cnt);  // fallback
            rem &= ~piece;
        }
    }
    __syncthreads();
    if (t < 256 && hk[t] != -1) {                 // B: one global find per root
        int g = gbase + hk[t];
        int r = find_root_c(L, g);
        hrs[t] = r;
        atomicAdd(&sizes[r], hcnt[t]);
    }
    __syncthreads();
    if (t < SWORDS && m) {                        // C: compress + exact ncomp
        uint64_t rem = m; int rk = 0;
        while (rem) {
            int s = __builtin_ctzll(rem);
            uint64_t rest = rem >> s;
            uint64_t nr = ~rest;
            int len = nr ? __builtin_ctzll(nr) : (64 - s);
            uint64_t piece = ((len >= 64) ? ~0ull : ((1ull << len) - 1)) << s;
            bool ini = !(s == 0 && cvL >= 0);
            if (ini) {
                int rl = wb + rk;
                int rloc = find_root_lds(par, rl);
                int sl = hash_find(rloc, hk);
                int r = (sl >= 0) ? hrs[sl] : walk_root(L, gbase + rloc);
                ast(&L[gbase + rl], r);
                if (r == gbase + rl) atomicAdd(ncomp_img, 1);
                ++rk;
            }
            rem &= ~piece;
        }
    }
}

// preload sizes[root] per hash slot into hsv (1 parallel RT per distinct root)
__device__ __forceinline__ void preload_sv(const int* sizes, int t,
                                           const int* hk, const int* hrs, int* hsv) {
    if (t < 256 && hk[t] != -1) hsv[t] = ald(&sizes[hrs[t]]);
}

// keep via LDS map (guard handled by caller); par/hash = this round's fg state
__device__ uint64_t keep_map(uint64_t m, int cvL, int wb, const int* par, int gbase,
                             const int* L, const int* sizes, int minsz,
                             const int* hk, const int* hrs, const int* hsv) {
    uint64_t res = m, rem = m; int rk = 0;
    while (rem) {
        int s = __builtin_ctzll(rem);
        uint64_t rest = rem >> s;
        uint64_t nr = ~rest;
        int len = nr ? __builtin_ctzll(nr) : (64 - s);
        uint64_t piece = ((len >= 64) ? ~0ull : ((1ull << len) - 1)) << s;
        bool ini = !(s == 0 && cvL >= 0);
        int rl = ini ? (wb + rk) : cvL; rk += ini ? 1 : 0;
        int rloc = find_root_lds(par, rl);
        int sl = hash_find(rloc, hk);
        int sz = (sl >= 0) ? hsv[sl] : ald(&sizes[walk_root(L, gbase + rloc)]);
        if (sz < minsz) res &= ~piece;
        rem &= ~piece;
    }
    return res;
}

// fill via LDS map (bg state)
__device__ uint64_t fill_map(uint64_t fg, int cvL, int wb, const int* par, int gbase,
                             const int* L, const int* sizes, int minsz,
                             const int* hk, const int* hrs, const int* hsv) {
    uint64_t bg = ~fg;
    uint64_t res = fg, rem = bg; int rk = 0;
    while (rem) {
        int s = __builtin_ctzll(rem);
        uint64_t rest = rem >> s;
        uint64_t nr = ~rest;
        int len = nr ? __builtin_ctzll(nr) : (64 - s);
        uint64_t piece = ((len >= 64) ? ~0ull : ((1ull << len) - 1)) << s;
        bool ini = !(s == 0 && cvL >= 0);
        int rl = ini ? (wb + rk) : cvL; rk += ini ? 1 : 0;
        int rloc = find_root_lds(par, rl);
        int sl = hash_find(rloc, hk);
        int sz = (sl >= 0) ? hsv[sl] : ald(&sizes[walk_root(L, gbase + rloc)]);
        if (sz < minsz) res |= piece;
        rem &= ~piece;
    }
    return res;
}

// global-path keep/fill for HALO words (L[rid] compressed by flatten phase C)
__device__ uint64_t keep_halo(uint64_t m, int cvg, int wrg, int nc,
                              const int* L, const int* sizes, int minsz) {
    uint64_t res = m;
    if (m && nc > 1) {
        uint64_t rem = m; int rk = 0;
        while (rem) {
            int s = __builtin_ctzll(rem);
            uint64_t rest = rem >> s;
            uint64_t nr = ~rest;
            int len = nr ? __builtin_ctzll(nr) : (64 - s);
            uint64_t piece = ((len >= 64) ? ~0ull : ((1ull << len) - 1)) << s;
            bool ini = !(s == 0 && cvg >= 0);
            int rid = ini ? (wrg + rk) : cvg; rk += ini ? 1 : 0;
            if (ald(&sizes[ald(&L[rid])]) < minsz) res &= ~piece;
            rem &= ~piece;
        }
    }
    return res;
}
__device__ uint64_t fill_halo(uint64_t fg, int cvg, int wrg,
                              const int* L, const int* sizes, int minsz) {
    uint64_t bg = ~fg;
    uint64_t res = fg;
    uint64_t rem = bg; int rk = 0;
    while (rem) {
        int s = __builtin_ctzll(rem);
        uint64_t rest = rem >> s;
        uint64_t nr = ~rest;
        int len = nr ? __builtin_ctzll(nr) : (64 - s);
        uint64_t piece = ((len >= 64) ? ~0ull : ((1ull << len) - 1)) << s;
        bool ini = !(s == 0 && cvg >= 0);
        int rid = ini ? (wrg + rk) : cvg; rk += ini ? 1 : 0;
        if (ald(&sizes[ald(&L[rid])]) < minsz) res |= piece;
        rem &= ~piece;
    }
    return res;
}

// one morph output word from an LDS window; gyTop = global row of local row 0
template <int R, bool ERODE>
__device__ uint64_t morph_word_lds(const uint64_t* buf, int lrow, int w, int gyTop) {
    const uint64_t BORDER = ERODE ? ~0ull : 0ull;
    uint64_t res = ERODE ? ~0ull : 0ull;
#pragma unroll
    for (int dy = -R; dy <= R; ++dy) {
        int lr = lrow + dy;
        int gy = gyTop + lr;
        if (gy < 0 || gy >= H) continue;       // image border rows = identity
        int v = R * R - dy * dy;
        int kx = 0;
        while ((kx + 1) * (kx + 1) <= v) ++kx;
        uint64_t cur = buf[lr * 8 + w];
        uint64_t prv = (w > 0) ? buf[lr * 8 + w - 1] : BORDER;
        uint64_t nxt = (w < 7) ? buf[lr * 8 + w + 1] : BORDER;
        uint64_t acc = cur;
#pragma unroll
        for (int dx = 1; dx <= kx; ++dx) {
            uint64_t right = (cur >> dx) | (nxt << (64 - dx));
            uint64_t left  = (cur << dx) | (prv >> (64 - dx));
            if (ERODE) acc &= right & left;
            else       acc |= right | left;
        }
        if (ERODE) res &= acc;
        else       res |= acc;
    }
    return res;
}

// ---------------------------------------------------------------------------
// Strip-local CCL body, run-id edition (t >= SWORDS pass m = 0 and barrier).
// LDS side-products sw/scarry/cntL/wbL AND par persist for later phases.
// ---------------------------------------------------------------------------
__device__ void strip_ccl_body(uint64_t m, uint64_t* sw, int* scarry,
                               int* cntL, int* wbL, int* par,
                               int blk, int t,
                               int* __restrict__ carry, int* __restrict__ wordrun,
                               int* __restrict__ L, int* __restrict__ sizes,
                               int* __restrict__ ncomp) {
    if (t < SWORDS) sw[t] = m;
    __syncthreads();

    if (t < SWORDS) {                   // per-word new-run count
        bool cont = (t & 7) ? ((sw[t - 1] >> 63) != 0) : false;
        int c = __popcll(m & ~(m << 1));
        if ((m & 1ull) && cont) --c;
        cntL[t] = c;
        wbL[t] = c;
    }
    __syncthreads();
    for (int off = 1; off < SWORDS; off <<= 1) {   // inclusive scan (128)
        int v = 0;
        if (t < SWORDS && t >= off) v = wbL[t - off];
        __syncthreads();
        if (t < SWORDS) wbL[t] += v;
        __syncthreads();
    }

    if (t < SROWS) {                    // per-row rid carries
        int cv = -1;
        for (int i = 0; i < 8; ++i) {
            int lw = t * 8 + i;
            scarry[lw] = cv;
            uint64_t w = sw[lw];
            if (w >> 63) { if (cntL[lw] > 0) cv = wbL[lw] - 1; }  // last start's rid
            else cv = -1;
        }
    }
    for (int i = t; i < MAXR; i += 256) par[i] = i;   // identity init
    __syncthreads();

    int cv = -1, wb = 0;
    uint64_t starts = 0ull;
    if (t < SWORDS) {
        cv = scarry[t];
        wb = wbL[t] - cntL[t];          // exclusive base
        ast(&carry[blk * SWORDS + t], (cv >= 0) ? (blk * MAXR + cv) : -1);
        ast(&wordrun[blk * SWORDS + t], blk * MAXR + wb);
        starts = m & ~((m << 1) | ((cv >= 0) ? 1ull : 0ull));
    }
    __syncthreads();

    if (t >= 8 && t < SWORDS && m) {    // intra-strip vertical unions
        uint64_t up = sw[t - 8];
        uint64_t cand = m & up;
        if (cand) {
            uint64_t curprev = (t & 7) ? sw[t - 1] : 0ull;
            uint64_t upprev  = (t & 7) ? sw[t - 9] : 0ull;
            uint64_t curl = (m << 1) | (curprev >> 63);
            uint64_t upl  = (up << 1) | (upprev >> 63);
            cand &= ~(curl & upl);
            int cvu = scarry[t - 8];
            int wbu = wbL[t - 8] - cntL[t - 8];
            uint64_t startsU = up & ~((up << 1) | ((cvu >= 0) ? 1ull : 0ull));
            while (cand) {
                int i = __builtin_ctzll(cand);
                int sP = run_of_lds(m, i, cv, starts, wb);
                int sQ = run_of_lds(up, i, cvu, startsU, wbu);
                merge_lds(par, sP, sQ);
                cand &= cand - 1;
            }
        }
    }
    __syncthreads();

    if (t < SWORDS) {                   // publish depth-1 trees (rid space)
        int g = blk * MAXR;
        uint64_t ss = starts;
        int rk = 0;
        while (ss) {
            int rid = wb + rk; ++rk;
            int r = find_root_lds(par, rid);
            ast(&L[g + rid], g + r);
            if (r == rid) ast(&sizes[g + rid], 0);
            ss &= ss - 1;
        }
    }
    if (t == 0 && (blk & 31) == 0) ast(&ncomp[blk >> 5], 0);  // 32 strips/image
}

// ---------------------------------------------------------------------------
// PER-IMAGE fence-free barrier with persistent epoch flags.
// ---------------------------------------------------------------------------
__device__ __forceinline__ void ibar(int img, int si, int ep, int phase) {
    int* base = g_flags + img * 32;
    __syncthreads();
    if (threadIdx.x == 0) {
        asm volatile("s_waitcnt vmcnt(0)" ::: "memory");
        ast(&base[si], ep + phase);
    }
    if (threadIdx.x < 32) {
        int spins = 0;
        while (ald(&base[threadIdx.x]) - ep < phase && ++spins < SPIN_LIMIT)
            __builtin_amdgcn_s_sleep(1);
    }
    __syncthreads();
}

// ---------------------------------------------------------------------------
// MEGA: whole pipeline, ONE kernel, 9 per-image barriers, run-id UF,
// per-strip LDS root cache. parS dedicated (27.7 KB total LDS, 2 blocks/CU).
// ---------------------------------------------------------------------------
__global__ __launch_bounds__(256, 2) void k_mega(
        const float4* __restrict__ in4, float* __restrict__ out,
        int* LA, int* sizesA, int* LB, int* sizesB,
        uint64_t* bits1, uint64_t* bits2, uint64_t* bits3,
        int* carryA, int* carryB, int* wordrunA, int* wordrunB,
        int* ncompA, int* ncompB) {
    __shared__ uint64_t sw[SWORDS];
    __shared__ int scarry[SWORDS];
    __shared__ int cntL[SWORDS];
    __shared__ int wbL[SWORDS];
    __shared__ int hk[256], hcnt[256], hrs[256], hsv[256];   // root hash (4 KB)
    __shared__ int shnc;
    __shared__ int parS[MAXR];                               // 16 KB, DEDICATED
    __shared__ union US {
        struct { uint64_t A[320]; uint64_t B[320]; } mo;     // 5 KB (morph)
        struct { uint64_t kb[80]; uint64_t db[64]; } kd;     // 1.1 KB (out)
    } U;
    int blk = blockIdx.x;
    int t = threadIdx.x;
    int img = blk >> 5, si = blk & 31;   // image id, strip-in-image
    int gb = blk * MAXR;                 // this strip's rid base
    int ep = ald(&g_flags[img * 32 + si]);   // epoch = own flag's last value

    // P0: threshold + pack, strip-local; words dropped into LDS sw for P1.
#pragma unroll
    for (int it = 0; it < 8; ++it) {
        int q = blk * (SPIX / 4) + it * 256 + t;           // quad index
        float4 v = in4[q];
        uint32_t nib = (v.x > 0.0f ? 1u : 0u) | (v.y > 0.0f ? 2u : 0u) |
                       (v.z > 0.0f ? 4u : 0u) | (v.w > 0.0f ? 8u : 0u);
        uint64_t val = (uint64_t)nib << (4 * (t & 15));
        val |= __shfl_xor(val, 1);
        val |= __shfl_xor(val, 2);
        val |= __shfl_xor(val, 4);
        val |= __shfl_xor(val, 8);
        if ((t & 15) == 0) {
            ast64(&bits1[q >> 4], val);                    // for merge halos
            sw[it * 16 + (t >> 4)] = val;
        }
    }
    __syncthreads();

    // P1: CCL1 strip phase (fg of bits1) -> set A
    {
        uint64_t m = (t < SWORDS) ? sw[t] : 0ull;
        strip_ccl_body(m, sw, scarry, cntL, wbL, parS, blk, t,
                       carryA, wordrunA, LA, sizesA, ncompA);
    }
    ibar(img, si, ep, 1);

    // P2: cross-strip merges (bits1, fg); up side from LDS, down side global
    if (t < 8 && si < 31) {
        int gw = (blk + 1) * SWORDS + t;     // below strip's row-0 word t
        uint64_t cur = ald64(&bits1[gw]);
        uint64_t curprev = t ? ald64(&bits1[gw - 1]) : 0ull;
        int cvc = ald(&carryA[gw]);
        int wrc = ald(&wordrunA[gw]);
        uint64_t up = sw[120 + t];
        uint64_t upprev = t ? sw[119 + t] : 0ull;
        int cvuL = scarry[120 + t];
        int cvu = cvuL >= 0 ? gb + cvuL : -1;
        int wru = gb + (wbL[120 + t] - cntL[120 + t]);
        uint64_t cand = cur & up;
        if (cand) {
            uint64_t curl = (cur << 1) | (curprev >> 63);
            uint64_t upl  = (up << 1) | (upprev >> 63);
            cand &= ~(curl & upl);
            while (cand) {
                int i = __builtin_ctzll(cand);
                int sP = run_of(cur, i, cvc, wrc);
                int sQ = run_of(up, i, cvu, wru);
                merge_uf(LA, sP, sQ);
                cand &= cand - 1;
            }
        }
    }
    ibar(img, si, ep, 2);

    // P3: flatten (fg) via LDS map — ~zero global loads on the hot path
    {
        uint64_t m = (t < SWORDS) ? sw[t] : 0ull;
        int cvL = (t < SWORDS) ? scarry[t] : -1;
        int wb = (t < SWORDS) ? (wbL[t] - cntL[t]) : 0;
        flatten_map(m, cvL, wb, parS, gb, LA, sizesA, &ncompA[img],
                    t, hk, hcnt, hrs);
    }
    ibar(img, si, ep, 3);

    // P4: remove_small_objects(2000,guard) via map -> bits2, + CCL2 strip (bg)
    {
        if (t == 0) shnc = ald(&ncompA[img]);
        preload_sv(sizesA, t, hk, hrs, hsv);
        __syncthreads();
        uint64_t m2 = 0ull;
        if (t < SWORDS) {
            uint64_t m1 = sw[t];
            int cvL = scarry[t];
            int wb = wbL[t] - cntL[t];
            uint64_t kw = (shnc > 1)
                ? keep_map(m1, cvL, wb, parS, gb, LA, sizesA, 2000, hk, hrs, hsv)
                : m1;
            ast64(&bits2[blk * SWORDS + t], kw);
            m2 = ~kw;
        }
        __syncthreads();                 // all keep_map par reads done before
        strip_ccl_body(m2, sw, scarry, cntL, wbL, parS, blk, t,
                       carryB, wordrunB, LB, sizesB, ncompB);
    }
    ibar(img, si, ep, 4);

    // P5: cross-strip merges (bits2, bg)
    if (t < 8 && si < 31) {
        int gw = (blk + 1) * SWORDS + t;
        uint64_t cur = ~ald64(&bits2[gw]);
        uint64_t curprev = t ? ~ald64(&bits2[gw - 1]) : 0ull;
        int cvc = ald(&carryB[gw]);
        int wrc = ald(&wordrunB[gw]);
        uint64_t up = sw[120 + t];
        uint64_t upprev = t ? sw[119 + t] : 0ull;
        int cvuL = scarry[120 + t];
        int cvu = cvuL >= 0 ? gb + cvuL : -1;
        int wru = gb + (wbL[120 + t] - cntL[120 + t]);
        uint64_t cand = cur & up;
        if (cand) {
            uint64_t curl = (cur << 1) | (curprev >> 63);
            uint64_t upl  = (up << 1) | (upprev >> 63);
            cand &= ~(curl & upl);
            while (cand) {
                int i = __builtin_ctzll(cand);
                int sP = run_of(cur, i, cvc, wrc);
                int sQ = run_of(up, i, cvu, wru);
                merge_uf(LB, sP, sQ);
                cand &= cand - 1;
            }
        }
    }
    ibar(img, si, ep, 5);

    // P6: flatten (bg) via LDS map
    {
        uint64_t m = (t < SWORDS) ? sw[t] : 0ull;
        int cvL = (t < SWORDS) ? scarry[t] : -1;
        int wb = (t < SWORDS) ? (wbL[t] - cntL[t]) : 0;
        flatten_map(m, cvL, wb, parS, gb, LB, sizesB, &ncompB[img],
                    t, hk, hcnt, hrs);
    }
    ibar(img, si, ep, 6);

    // P7: fill_holes(<301) + erode(d2) + opening(d5) + CCL3 strip -> bits3, A
    {
        preload_sv(sizesB, t, hk, hrs, hsv);
        __syncthreads();
        int gyTop = si * 16 - 12;
        for (int lw = t; lw < 320; lw += 256) {
            int gy = gyTop + (lw >> 3);
            int w = lw & 7;
            uint64_t v = 0;
            if (gy >= 0 && gy < H) {
                if (lw >= 96 && lw < 224) {          // own strip: LDS map path
                    int ti = lw - 96;
                    uint64_t fg = ~sw[ti];           // sw = bg mask -> fg
                    int cvL = scarry[ti];
                    int wb = wbL[ti] - cntL[ti];
                    v = fill_map(fg, cvL, wb, parS, gb, LB, sizesB, 301,
                                 hk, hrs, hsv);      // parS dedicated: no alias
                } else {                             // halo: global path
                    int gw = img * 4096 + gy * 8 + w;
                    uint64_t fg = ald64(&bits2[gw]);
                    int cvg = ald(&carryB[gw]);
                    int wrg = ald(&wordrunB[gw]);
                    v = fill_halo(fg, cvg, wrg, LB, sizesB, 301);
                }
            }
            U.mo.A[lw] = v;
        }
        __syncthreads();
        for (int lw = t; lw < 320; lw += 256) {              // erode disk(2)
            int lr = lw >> 3;
            if (lr >= 2 && lr <= 37) U.mo.B[lw] = morph_word_lds<2, true>(U.mo.A, lr, lw & 7, gyTop);
        }
        __syncthreads();
        for (int lw = t; lw < 320; lw += 256) {              // erode disk(5)
            int lr = lw >> 3;
            if (lr >= 7 && lr <= 32) U.mo.A[lw] = morph_word_lds<5, true>(U.mo.B, lr, lw & 7, gyTop);
        }
        __syncthreads();
        for (int lw = t; lw < 320; lw += 256) {              // dilate disk(5)
            int lr = lw >> 3;
            if (lr >= 12 && lr <= 27) U.mo.B[lw] = morph_word_lds<5, false>(U.mo.A, lr, lw & 7, gyTop);
        }
        __syncthreads();
        uint64_t m3 = 0ull;
        if (t < SWORDS) {
            m3 = U.mo.B[t + 96];        // local rows 12..27 = this strip
            ast64(&bits3[blk * SWORDS + t], m3);
        }
        __syncthreads();                // mo.B reads done before par rewrite
        strip_ccl_body(m3, sw, scarry, cntL, wbL, parS, blk, t,
                       carryA, wordrunA, LA, sizesA, ncompA);
    }
    ibar(img, si, ep, 7);

    // P8: cross-strip merges (bits3, fg)
    if (t < 8 && si < 31) {
        int gw = (blk + 1) * SWORDS + t;
        uint64_t cur = ald64(&bits3[gw]);
        uint64_t curprev = t ? ald64(&bits3[gw - 1]) : 0ull;
        int cvc = ald(&carryA[gw]);
        int wrc = ald(&wordrunA[gw]);
        uint64_t up = sw[120 + t];
        uint64_t upprev = t ? sw[119 + t] : 0ull;
        int cvuL = scarry[120 + t];
        int cvu = cvuL >= 0 ? gb + cvuL : -1;
        int wru = gb + (wbL[120 + t] - cntL[120 + t]);
        uint64_t cand = cur & up;
        if (cand) {
            uint64_t curl = (cur << 1) | (curprev >> 63);
            uint64_t upl  = (up << 1) | (upprev >> 63);
            cand &= ~(curl & upl);
            while (cand) {
                int i = __builtin_ctzll(cand);
                int sP = run_of(cur, i, cvc, wrc);
                int sQ = run_of(up, i, cvu, wru);
                merge_uf(LA, sP, sQ);
                cand &= cand - 1;
            }
        }
    }
    ibar(img, si, ep, 8);

    // P9: flatten (bits3, fg) via LDS map
    {
        uint64_t m = (t < SWORDS) ? sw[t] : 0ull;
        int cvL = (t < SWORDS) ? scarry[t] : -1;
        int wb = (t < SWORDS) ? (wbL[t] - cntL[t]) : 0;
        flatten_map(m, cvL, wb, parS, gb, LA, sizesA, &ncompA[img],
                    t, hk, hcnt, hrs);
    }
    ibar(img, si, ep, 9);

    // P10: remove_small_objects(2000,guard) + dilate(d1) + float4 out.
    {
        if (t == 0) shnc = ald(&ncompA[img]);
        preload_sv(sizesA, t, hk, hrs, hsv);
        __syncthreads();
        for (int k = 0; k < 2; ++k) {
            int s8 = 2 * si + k;
            int y0 = s8 * 8;
            if (t < 80) {
                int lr = t >> 3, w = t & 7;
                int gy = y0 - 1 + lr;
                uint64_t v = 0;
                if (gy >= 0 && gy < H) {
                    int rel = gy - 16 * si;
                    if (rel >= 0 && rel < 16) {      // own strip: LDS map path
                        int ti = rel * 8 + w;
                        uint64_t m = sw[ti];
                        int cvL = scarry[ti];
                        int wb = wbL[ti] - cntL[ti];
                        v = (shnc > 1)
                            ? keep_map(m, cvL, wb, parS, gb, LA, sizesA, 2000,
                                       hk, hrs, hsv)   // parS dedicated: no alias
                            : m;
                    } else {                         // halo row: global path
                        int gw = img * 4096 + gy * 8 + w;
                        uint64_t m = ald64(&bits3[gw]);
                        int cvg = ald(&carryA[gw]);
                        int wrg = ald(&wordrunA[gw]);
                        v = keep_halo(m, cvg, wrg, shnc, LA, sizesA, 2000);
                    }
                }
                U.kd.kb[t] = v;
            }
            __syncthreads();
            if (t < 64) {
                int r = t >> 3, w = t & 7;
                uint64_t cur = U.kd.kb[(r + 1) * 8 + w];
                uint64_t up  = U.kd.kb[r * 8 + w];
                uint64_t dn  = U.kd.kb[(r + 2) * 8 + w];
                uint64_t prv = w ? U.kd.kb[(r + 1) * 8 + w - 1] : 0ull;
                uint64_t nxt = (w < 7) ? U.kd.kb[(r + 1) * 8 + w + 1] : 0ull;
                U.kd.db[t] = cur | up | dn | (cur << 1) | (prv >> 63) |
                             (cur >> 1) | (nxt << 63);
            }
            __syncthreads();
            {
                int q0 = t * 16;                    // 16 consecutive px/thread
                uint64_t wd = U.kd.db[q0 >> 6];
                int sh = q0 & 63;
                float4* o = (float4*)(out + (size_t)img * HW + (size_t)y0 * W + q0);
#pragma unroll
                for (int kk = 0; kk < 4; ++kk) {
                    uint32_t nib = (uint32_t)(wd >> (sh + kk * 4)) & 0xFu;
                    float4 f;
                    f.x = (nib & 1u) ? 1.0f : 0.0f;
                    f.y = (nib & 2u) ? 1.0f : 0.0f;
                    f.z = (nib & 4u) ? 1.0f : 0.0f;
                    f.w = (nib & 8u) ? 1.0f : 0.0f;
                    o[kk] = f;
                }
            }
            __syncthreads();
        }
    }
}

// ---------------------------------------------------------------------------
// Host side — exactly ONE dispatch (flags are persistent device globals)
// ---------------------------------------------------------------------------
extern "C" void kernel_launch(void* const* d_in, const int* in_sizes, int n_in,
                              void* d_out, int out_size, void* d_ws, size_t ws_size,
                              hipStream_t stream) {
    const float* in = (const float*)d_in[0];
    float* out = (float*)d_out;

    uint8_t* ws = (uint8_t*)d_ws;
    int* LA      = (int*)ws;                                  // 8 MB (rid space)
    int* sizesA  = LA + NR;                                   // 8 MB
    int* LB      = sizesA + NR;                               // 8 MB
    int* sizesB  = LB + NR;                                   // 8 MB
    uint64_t* bits1 = (uint64_t*)(sizesB + NR);               // 512 KB
    uint64_t* bits2 = bits1 + NWORDS;                         // 512 KB
    uint64_t* bits3 = bits2 + NWORDS;                         // 512 KB
    int* carryA   = (int*)(bits3 + NWORDS);                   // 256 KB
    int* carryB   = carryA + NWORDS;                          // 256 KB
    int* wordrunA = carryB + NWORDS;                          // 256 KB
    int* wordrunB = wordrunA + NWORDS;                        // 256 KB
    int* ncompA   = wordrunB + NWORDS;                        // 64 B
    int* ncompB   = ncompA + BATCH;                           // 64 B

    k_mega<<<NSTRIPS, 256, 0, stream>>>((const float4*)in, out,
                                        LA, sizesA, LB, sizesB,
                                        bits1, bits2, bits3,
                                        carryA, carryB, wordrunA, wordrunB,
                                        ncompA, ncompB);
}